// Round 6
// baseline (575.554 us; speedup 1.0000x reference)
//
#include <hip/hip_runtime.h>

#define BB 256
#define TT 512
#define NN 128
#define GO_IDX 1
#define EOS_IDX 2
#define TSPLIT 360            // bp steps t in [1,TSPLIT) in LDS; [TSPLIT,512) spilled (ws or consumed unary rows)
#define LAG 2                 // bp waves trail the value chain by LAG steps
#define NEGV (-10000.0f)
// padded alpha slot: x + (x>>5)*4  -> quarter bases at 0,36,72,108 (banks 0,4,8,12; 16B aligned)
#define ASLOT(x) ((x) + (((x) >> 5) << 2))

// step barrier: drain LDS only (ring/bps/prob), leave global prefetch loads in flight.
#define STEP_BARRIER() asm volatile("s_waitcnt lgkmcnt(0)\n\ts_barrier" ::: "memory")

typedef float f32x2 __attribute__((ext_vector_type(2)));

// packed f32 add (VOP3P) — same adds as scalar, half the instructions, bit-exact
__device__ __forceinline__ f32x2 pk_add(f32x2 a, f32x2 b) {
    f32x2 d;
    asm("v_pk_add_f32 %0, %1, %2" : "=v"(d) : "v"(a), "v"(b));
    return d;
}

// ---------- DPP quad_perm helpers ----------
__device__ __forceinline__ float dpp_xor1_f(float x) {      // quad_perm [1,0,3,2]
    return __int_as_float(__builtin_amdgcn_update_dpp(0, __float_as_int(x), 0xB1, 0xF, 0xF, true));
}
__device__ __forceinline__ float dpp_xor2_f(float x) {      // quad_perm [2,3,0,1]
    return __int_as_float(__builtin_amdgcn_update_dpp(0, __float_as_int(x), 0x4E, 0xF, 0xF, true));
}
__device__ __forceinline__ int dpp_xor1_i(int x) {
    return __builtin_amdgcn_update_dpp(0, x, 0xB1, 0xF, 0xF, true);
}
__device__ __forceinline__ int dpp_xor2_i(int x) {
    return __builtin_amdgcn_update_dpp(0, x, 0x4E, 0xF, 0xF, true);
}

// ---------- producer/consumer split Viterbi ----------
// 1024 threads. Waves 0..7 (grp=0, "value waves"): serial value-only chain
//   alpha[t+1] = max_prev(alpha[t]+tr) + P[t]  — pk_add + fmax tree, NO index
//   tracking, writes an alpha ring (depth 4). Runs at s_setprio(1).
// Waves 8..15 (grp=1, "bp waves"): trail LAG=2 steps behind, replay the EXACT
//   proven add/compare/index chain on ring slot (t-LAG)&3 and store bps.
//   Also own log_softmax staging + raw prefetch (all off the critical chain).
// Ring safety: interval t writes slot (t+1)&3, value reads t&3, bp reads
//   (t-2)&3 — pairwise distinct mod 4; reuse is >=2 barriers separated.
template <int USE_WS>
__global__ __launch_bounds__(1024) void viterbi_kernel(
    float* __restrict__ u,               // [B,T,N] RAW unaries
    const float* __restrict__ trans,     // [1,N,N] trans0[cur][prev]
    const int*   __restrict__ lengths_raw,
    float* __restrict__ out,             // [B*T] preds then [B] scores
    unsigned char* __restrict__ ws)      // spill: [B][152][128] bytes when USE_WS
{
    __shared__ unsigned char bps[(TSPLIT - 1) * NN];   // 45952 B (steps 1..359 at row t-1)
    __shared__ __align__(16) float prob[2][16][NN];    // 16384 B, normalized rows (dbuf); reused as bp cache
    __shared__ __align__(16) float ring[4][144];       // 2304 B, alpha ring, padded slots
    __shared__ float fin_v[2];
    __shared__ int   fin_i[2];

    const int tid  = threadIdx.x;
    const int b    = blockIdx.x;
    const int grp  = tid >> 9;             // 0 = value waves, 1 = bp waves
    const int lt   = tid & 511;            // local tid within group
    const int wv   = lt >> 6;              // wave within group 0..7
    const int lane = tid & 63;
    const int q    = lt & 3;               // prev-quarter owned by this lane
    const int cur  = lt >> 2;              // tag owned by this quad (0..127)
    const int hw   = lt >> 5;              // half-wave 0..15 (bp group: lsm row owner)
    const int l32  = tid & 31;

    int len;
    {
        int probe = lengths_raw[1];        // ==0 iff int64 (lengths >= 256 > 0)
        len = (probe == 0) ? lengths_raw[2 * b] : lengths_raw[b];
    }

    float* pb = u + (size_t)b * TT * NN;
    const float4* pb4 = (const float4*)pb;
    unsigned char* spb = USE_WS ? (ws + (size_t)b * ((TT - TSPLIT) * NN)) : (unsigned char*)pb;

    // trans chunk in register PAIRS (shared layout for both groups):
    // tr2[c*4+j] = trans0[cur][q*32 + c*8 + 2j .. +1]
    f32x2 tr2[16];
    {
        const float4* t4 = (const float4*)(trans + cur * NN + q * 32);
#pragma unroll
        for (int i = 0; i < 8; ++i) {
            float4 v = t4[i];
            f32x2 lo; lo.x = v.x; lo.y = v.y;
            f32x2 hi; hi.x = v.z; hi.y = v.w;
            tr2[2 * i]     = lo;
            tr2[2 * i + 1] = hi;
        }
    }

    if (tid < NN) ring[0][ASLOT(tid)] = (tid == GO_IDX) ? 0.0f : NEGV;

    // per-row log_softmax, bitwise-identical to the proven math (bp waves only)
    auto normrow = [&](float4 v, float* dstrow) {
        float m = fmaxf(fmaxf(v.x, v.y), fmaxf(v.z, v.w));
#pragma unroll
        for (int off = 16; off; off >>= 1) m = fmaxf(m, __shfl_xor(m, off, 64));
        float s = expf(v.x - m) + expf(v.y - m) + expf(v.z - m) + expf(v.w - m);
#pragma unroll
        for (int off = 16; off; off >>= 1) s += __shfl_xor(s, off, 64);
        float ls = logf(s);
        ((float4*)dstrow)[l32] =
            make_float4((v.x - m) - ls, (v.y - m) - ls, (v.z - m) - ls, (v.w - m) - ls);
    };

    // prologue (bp waves): rows 0..15 -> buf0; rows 16..31 -> R
    float4 R;
    if (grp == 1) {
        R = pb4[hw * 32 + l32];
        normrow(R, &prob[0][hw][0]);
        R = pb4[(16 + hw) * 32 + l32];
    }
    __syncthreads();

    if (grp == 0) __builtin_amdgcn_s_setprio(1);   // favor the serial value chain

    const int lenP = len + LAG;                    // LAG epilogue intervals flush bp tail
    const int nG = (lenP + 15) >> 4;
    for (int g = 0; g < nG; ++g) {
        const int tb = g << 4;
        if (grp == 1) {
            // normalize rows of group g+1 (loaded last group) -> buf[(g+1)&1]
            normrow(R, &prob[(g + 1) & 1][hw][0]);
            // issue raw loads for group g+2 (stay in flight across step barriers)
            int rr = tb + 32 + hw;
            if (rr > TT - 1) rr = TT - 1;          // clamped row never normalized/used
            R = pb4[rr * 32 + l32];
        }
#pragma unroll 4
        for (int k = 0; k < 16; ++k) {
            const int t = tb + k;
            if (t < lenP) {                        // uniform per block
                if (grp == 0) {
                    if (t < len) {
                        // ---- value step: max only, index-free ----
                        const float Pv = prob[g & 1][k][cur];   // broadcast ds_read_b32
                        const float* ra = ring[t & 3];
                        float*       wa = ring[(t + 1) & 3];
                        const float4* a4 = (const float4*)(ra + q * 36);
                        float bm[4];
#pragma unroll
                        for (int c = 0; c < 4; ++c) {
                            float4 a0 = a4[c * 2], a1 = a4[c * 2 + 1];
                            f32x2 p0; p0.x = a0.x; p0.y = a0.y;
                            f32x2 p1; p1.x = a0.z; p1.y = a0.w;
                            f32x2 p2; p2.x = a1.x; p2.y = a1.y;
                            f32x2 p3; p3.x = a1.z; p3.y = a1.w;
                            f32x2 s0 = pk_add(p0, tr2[c * 4 + 0]);
                            f32x2 s1 = pk_add(p1, tr2[c * 4 + 1]);
                            f32x2 s2 = pk_add(p2, tr2[c * 4 + 2]);
                            f32x2 s3 = pk_add(p3, tr2[c * 4 + 3]);
                            float m01 = fmaxf(fmaxf(s0.x, s0.y), fmaxf(s1.x, s1.y));
                            float m23 = fmaxf(fmaxf(s2.x, s2.y), fmaxf(s3.x, s3.y));
                            bm[c] = fmaxf(m01, m23);
                        }
                        float M = fmaxf(fmaxf(bm[0], bm[1]), fmaxf(bm[2], bm[3]));
                        M = fmaxf(M, dpp_xor1_f(M));           // quad combine, value-only
                        M = fmaxf(M, dpp_xor2_f(M));
                        if (q == 0) wa[ASLOT(cur)] = M + Pv;
                    }
                } else {
                    const int tbp = t - LAG;       // lagged bp step
                    if (tbp >= 1 && tbp < len) {
                        // ---- bp step: EXACT proven add/compare/index chain ----
                        const float* ra = ring[tbp & 3];
                        const float4* a4 = (const float4*)(ra + q * 36);
                        float bv[4]; int bi4[4];
#pragma unroll
                        for (int c = 0; c < 4; ++c) {  // 4 chains x 8 prevs, ascending strict >
                            float4 a0 = a4[c * 2], a1 = a4[c * 2 + 1];
                            f32x2 p0; p0.x = a0.x; p0.y = a0.y;
                            f32x2 p1; p1.x = a0.z; p1.y = a0.w;
                            f32x2 p2; p2.x = a1.x; p2.y = a1.y;
                            f32x2 p3; p3.x = a1.z; p3.y = a1.w;
                            f32x2 s0 = pk_add(p0, tr2[c * 4 + 0]);
                            f32x2 s1 = pk_add(p1, tr2[c * 4 + 1]);
                            f32x2 s2 = pk_add(p2, tr2[c * 4 + 2]);
                            f32x2 s3 = pk_add(p3, tr2[c * 4 + 3]);
                            const int base = c * 8;
                            bv[c] = s0.x; bi4[c] = base + 0;
                            float x;
                            x = s0.y; if (x > bv[c]) { bv[c] = x; bi4[c] = base + 1; }
                            x = s1.x; if (x > bv[c]) { bv[c] = x; bi4[c] = base + 2; }
                            x = s1.y; if (x > bv[c]) { bv[c] = x; bi4[c] = base + 3; }
                            x = s2.x; if (x > bv[c]) { bv[c] = x; bi4[c] = base + 4; }
                            x = s2.y; if (x > bv[c]) { bv[c] = x; bi4[c] = base + 5; }
                            x = s3.x; if (x > bv[c]) { bv[c] = x; bi4[c] = base + 6; }
                            x = s3.y; if (x > bv[c]) { bv[c] = x; bi4[c] = base + 7; }
                        }
                        float best = bv[0]; int bp = bi4[0];
#pragma unroll
                        for (int c = 1; c < 4; ++c) { if (bv[c] > best) { best = bv[c]; bp = bi4[c]; } }
                        bp += q * 32;              // absolute prev index

                        // DPP quad combine (value + index), proven tie-break:
                        // even q: strict > keeps own; odd q: >= takes lower partner.
                        float v1 = dpp_xor1_f(best); int b1 = dpp_xor1_i(bp);
                        bool  t1 = (q & 1) ? (v1 >= best) : (v1 > best);
                        float m1 = t1 ? v1 : best;   int p1i = t1 ? b1 : bp;
                        float v2 = dpp_xor2_f(m1);   int b2 = dpp_xor2_i(p1i);
                        bool  t2 = (q & 2) ? (v2 >= m1) : (v2 > m1);
                        int BP = t2 ? b2 : p1i;

                        if (q == 0) {
                            if (tbp < TSPLIT) bps[(tbp - 1) * NN + cur] = (unsigned char)BP;
                            else if (USE_WS)  spb[(tbp - TSPLIT) * NN + cur] = (unsigned char)BP;
                            else              spb[(size_t)tbp * 512 + cur] = (unsigned char)BP;
                        }
                    }
                }
                STEP_BARRIER();    // lgkmcnt(0) only — global prefetch stays in flight
            }
        }
    }

    if (grp == 0) __builtin_amdgcn_s_setprio(0);

    __threadfence();   // spilled bp global writes visible to this block's readers

    // terminal: argmax(alpha[len] + trans0[EOS][:]), first-max tie-break
    if (tid < NN) {
        float v = ring[len & 3][ASLOT(tid)] + trans[EOS_IDX * NN + tid];
        int idx = tid;
#pragma unroll
        for (int off = 32; off; off >>= 1) {
            float ov = __shfl_xor(v, off, 64);
            int   oi = __shfl_xor(idx, off, 64);
            if (ov > v || (ov == v && oi < idx)) { v = ov; idx = oi; }
        }
        if (lane == 0) { fin_v[wv] = v; fin_i[wv] = idx; }
    }
    __syncthreads();   // fin ready; full drain of forward traffic

    const int lenU = __builtin_amdgcn_readfirstlane(len);

    for (int t = lenU + tid; t < TT; t += 1024) out[(size_t)b * TT + t] = 0.0f;

    // stage spilled bp steps [TSPLIT, TSPLIT+128) into the (now free) prob LDS.
    {
        unsigned int* cache = (unsigned int*)&prob[0][0][0];          // 16384 B, exact fit
        const volatile unsigned int* src = (const volatile unsigned int*)spb;
        for (int i = tid; i < 128 * 32; i += 1024) {
            if (USE_WS) cache[i] = src[(size_t)(i >> 5) * 32 + (i & 31)];
            else        cache[i] = src[(size_t)(TSPLIT + (i >> 5)) * 128 + (i & 31)];
        }
    }
    __syncthreads();

    // terminal winner (uniform across threads)
    float sc; int T0;
    {
        float v0 = fin_v[0], v1 = fin_v[1];
        int   i0 = fin_i[0], i1 = fin_i[1];
        if (v1 > v0) { sc = v1; T0 = i1; }
        else         { sc = v0; T0 = i0; }
    }
    if (tid == 0) {
        out[(size_t)BB * TT + b] = sc;
        out[(size_t)b * TT + (lenU - 1)] = (float)T0;
    }

    // ---------- parallel hypothesis backtrace (value waves; 8 segments) ----------
    const unsigned char* cacheb = (const unsigned char*)&prob[0][0][0];
    unsigned char* lt_tab = (unsigned char*)&ring[0][0];  // last_tag[8][128] overlay (ring dead)
    unsigned char* Harr   = lt_tab + 1024;                // H[8] overlay

    const int s  = wv;                     // segment id 0..7
    const int A  = lenU - 1 - 64 * s;      // anchor time of this segment
    const int h0 = lane;                   // hypothesis tags
    const int h1 = 64 + lane;
    const int Jmax = (A < 64) ? A : 64;    // links to follow (A<1 -> none)

    unsigned int rec0[16], rec1[16];
    if (grp == 0) {
#pragma unroll
        for (int i = 0; i < 16; ++i) { rec0[i] = 0u; rec1[i] = 0u; }

        int c0 = h0, c1 = h1;
#pragma unroll
        for (int j = 1; j <= 64; ++j) {
            if (j <= Jmax) {                   // wave-uniform
                const int x = A - j + 1;       // step whose bp we read -> tag at time A-j
                int n0, n1;
                if (x < TSPLIT) {
                    n0 = bps[(x - 1) * NN + c0];
                    n1 = bps[(x - 1) * NN + c1];
                } else if (x < TSPLIT + 128) {
                    n0 = cacheb[(x - TSPLIT) * NN + c0];
                    n1 = cacheb[(x - TSPLIT) * NN + c1];
                } else {
                    if (USE_WS) {
                        n0 = ((const volatile unsigned char*)spb)[(size_t)(x - TSPLIT) * NN + c0];
                        n1 = ((const volatile unsigned char*)spb)[(size_t)(x - TSPLIT) * NN + c1];
                    } else {
                        n0 = ((const volatile unsigned char*)spb)[(size_t)x * 512 + c0];
                        n1 = ((const volatile unsigned char*)spb)[(size_t)x * 512 + c1];
                    }
                }
                c0 = n0; c1 = n1;
                rec0[(j - 1) >> 2] |= (unsigned int)c0 << (((j - 1) & 3) * 8);
                rec1[(j - 1) >> 2] |= (unsigned int)c1 << (((j - 1) & 3) * 8);
            }
        }
        if (A >= 65) {                         // tag at A-64 feeds segment s+1's stitch
            lt_tab[s * NN + h0] = (unsigned char)c0;
            lt_tab[s * NN + h1] = (unsigned char)c1;
        }
    }
    __syncthreads();

    if (tid == 0) {
        int H = T0;
        Harr[0] = (unsigned char)H;
#pragma unroll
        for (int ss = 1; ss < 8; ++ss) {
            if (lenU - 1 - 64 * ss >= 1) {
                H = lt_tab[(ss - 1) * NN + H];
                Harr[ss] = (unsigned char)H;
            }
        }
    }
    __syncthreads();

    if (grp == 0 && A >= 1) {
        const int Hs = Harr[s];
        if (h0 == Hs) {
#pragma unroll
            for (int j = 1; j <= 64; ++j)
                if (j <= Jmax)
                    out[(size_t)b * TT + (A - j)] =
                        (float)((rec0[(j - 1) >> 2] >> (((j - 1) & 3) * 8)) & 255u);
        }
        if (h1 == Hs) {
#pragma unroll
            for (int j = 1; j <= 64; ++j)
                if (j <= Jmax)
                    out[(size_t)b * TT + (A - j)] =
                        (float)((rec1[(j - 1) >> 2] >> (((j - 1) & 3) * 8)) & 255u);
        }
    }
}

extern "C" void kernel_launch(void* const* d_in, const int* in_sizes, int n_in,
                              void* d_out, int out_size, void* d_ws, size_t ws_size,
                              hipStream_t stream) {
    float*       unaries = (float*)d_in[0];
    const float* trans   = (const float*)d_in[1];
    const int*   lengths = (const int*)d_in[2];
    float* out = (float*)d_out;
    unsigned char* ws = (unsigned char*)d_ws;

    const size_t need = (size_t)BB * (TT - TSPLIT) * NN;   // 4,980,736 B
    if (ws != nullptr && ws_size >= need) {
        hipLaunchKernelGGL(HIP_KERNEL_NAME(viterbi_kernel<1>), dim3(BB), dim3(1024), 0, stream,
                           unaries, trans, lengths, out, ws);
    } else {
        hipLaunchKernelGGL(HIP_KERNEL_NAME(viterbi_kernel<0>), dim3(BB), dim3(1024), 0, stream,
                           unaries, trans, lengths, out, ws);
    }
}

// Round 7
// 574.572 us; speedup vs baseline: 1.0017x; 1.0017x over previous
//
#include <hip/hip_runtime.h>

#define BB 256
#define TT 512
#define NN 128
#define GO_IDX 1
#define EOS_IDX 2
#define TSPLIT 368            // bp steps t in [1,TSPLIT) in LDS; [TSPLIT,512) spilled (ws or consumed unary rows)
#define NEGV (-10000.0f)
// padded alpha slot: x + (x>>5)*4  -> quarter bases at 0,36,72,108 (banks 0,4,8,12; 16B aligned)
#define ASLOT(x) ((x) + (((x) >> 5) << 2))

// step barrier: drain LDS only (alpha/bps/prob), leave global prefetch loads in flight.
#define STEP_BARRIER() asm volatile("s_waitcnt lgkmcnt(0)\n\ts_barrier" ::: "memory")

// ---------- DPP quad_perm helpers ----------
__device__ __forceinline__ float dpp_xor1_f(float x) {      // quad_perm [1,0,3,2]
    return __int_as_float(__builtin_amdgcn_update_dpp(0, __float_as_int(x), 0xB1, 0xF, 0xF, true));
}
__device__ __forceinline__ float dpp_xor2_f(float x) {      // quad_perm [2,3,0,1]
    return __int_as_float(__builtin_amdgcn_update_dpp(0, __float_as_int(x), 0x4E, 0xF, 0xF, true));
}
__device__ __forceinline__ int dpp_xor1_i(int x) {
    return __builtin_amdgcn_update_dpp(0, x, 0xB1, 0xF, 0xF, true);
}
__device__ __forceinline__ int dpp_xor2_i(int x) {
    return __int_as_float(0), __builtin_amdgcn_update_dpp(0, x, 0x4E, 0xF, 0xF, true);
}

// ---------- fused kernel: 2-curs-per-lane Viterbi (halved LDS traffic) ----------
// 512 threads. Waves 0..3 "compute": quad cp (4 lanes, q = prev-quarter) handles
// curs cp AND cp+64 — reads its 32-alpha quarter ONCE (8 ds_read_b128), runs the
// exact round-2 add/compare/index chain twice (two tr rows in registers).
// After the DPP butterflies all 4 quad lanes hold (M,BP) for both curs, so
// q0/q1 write the two alphas and q2/q3 write the two bps: 1 LDS op per lane.
// Waves 4..7 "helpers": log_softmax staging + raw prefetch only (off-chain).
// Net per step: 32 ds_read_b128 (32 KB return) vs round-2's 64 (64 KB).
template <int USE_WS>
__global__ __launch_bounds__(512) void viterbi_kernel(
    float* __restrict__ u,               // [B,T,N] RAW unaries
    const float* __restrict__ trans,     // [1,N,N] trans0[cur][prev]
    const int*   __restrict__ lengths_raw,
    float* __restrict__ out,             // [B*T] preds then [B] scores
    unsigned char* __restrict__ ws)      // spill: [B][144][128] bytes when USE_WS
{
    __shared__ unsigned char bps[(TSPLIT - 1) * NN];   // 46976 B (steps 1..367 at row t-1)
    __shared__ __align__(16) float prob[2][16][NN];    // 16384 B, normalized rows (dbuf); reused as bp cache
    __shared__ __align__(16) float alpha[2][144];      // 1152 B; reused as last_tag/H tables in epilogue
    __shared__ float fin_v[2];
    __shared__ int   fin_i[2];

    const int tid  = threadIdx.x;
    const int b    = blockIdx.x;
    const int wv   = tid >> 6;             // wave 0..7
    const int lane = tid & 63;
    const bool comp = (tid < 256);         // waves 0..3 compute, 4..7 helpers
    const int q    = tid & 3;              // prev-quarter owned by this lane (compute)
    const int cp   = (tid & 255) >> 2;     // cur-pair id 0..63: curs cp and cp+64
    const int hw2  = (tid & 255) >> 5;     // helper half-wave 0..7: rows hw2, hw2+8
    const int l32  = tid & 31;

    int len;
    {
        int probe = lengths_raw[1];        // ==0 iff int64 (lengths >= 256 > 0)
        len = (probe == 0) ? lengths_raw[2 * b] : lengths_raw[b];
    }

    float* pb = u + (size_t)b * TT * NN;
    const float4* pb4 = (const float4*)pb;
    unsigned char* spb = USE_WS ? (ws + (size_t)b * ((TT - TSPLIT) * NN)) : (unsigned char*)pb;

    // two trans rows in registers (compute lanes): trA = trans0[cp][q*32+j],
    // trB = trans0[cp+64][q*32+j], j in [0,32)
    float trA[32], trB[32];
    if (comp) {
        const float4* tA = (const float4*)(trans + cp * NN + q * 32);
        const float4* tB = (const float4*)(trans + (cp + 64) * NN + q * 32);
#pragma unroll
        for (int i = 0; i < 8; ++i) {
            float4 va = tA[i];
            trA[4*i+0] = va.x; trA[4*i+1] = va.y; trA[4*i+2] = va.z; trA[4*i+3] = va.w;
            float4 vb = tB[i];
            trB[4*i+0] = vb.x; trB[4*i+1] = vb.y; trB[4*i+2] = vb.z; trB[4*i+3] = vb.w;
        }
    }

    if (tid < NN) alpha[0][ASLOT(tid)] = (tid == GO_IDX) ? 0.0f : NEGV;

    // per-row log_softmax, bitwise-identical to the proven math (helpers only)
    auto normrow = [&](float4 v, float* dstrow) {
        float m = fmaxf(fmaxf(v.x, v.y), fmaxf(v.z, v.w));
#pragma unroll
        for (int off = 16; off; off >>= 1) m = fmaxf(m, __shfl_xor(m, off, 64));
        float s = expf(v.x - m) + expf(v.y - m) + expf(v.z - m) + expf(v.w - m);
#pragma unroll
        for (int off = 16; off; off >>= 1) s += __shfl_xor(s, off, 64);
        float ls = logf(s);
        ((float4*)dstrow)[l32] =
            make_float4((v.x - m) - ls, (v.y - m) - ls, (v.z - m) - ls, (v.w - m) - ls);
    };

    // exact round-2 per-cur chain: 4 chains x 8 prevs ascending strict >, then
    // chain-combine strict >, then DPP quad combine with proven tie-break.
    auto curchain = [&](const float4* av, const float* tr, float& Mo, int& BPo) {
        float bv[4]; int bi4[4];
#pragma unroll
        for (int c = 0; c < 4; ++c) {
            float4 a0 = av[c * 2], a1 = av[c * 2 + 1];
            const int base = c * 8;
            bv[c] = a0.x + tr[base + 0]; bi4[c] = base + 0;
            float x;
            x = a0.y + tr[base + 1]; if (x > bv[c]) { bv[c] = x; bi4[c] = base + 1; }
            x = a0.z + tr[base + 2]; if (x > bv[c]) { bv[c] = x; bi4[c] = base + 2; }
            x = a0.w + tr[base + 3]; if (x > bv[c]) { bv[c] = x; bi4[c] = base + 3; }
            x = a1.x + tr[base + 4]; if (x > bv[c]) { bv[c] = x; bi4[c] = base + 4; }
            x = a1.y + tr[base + 5]; if (x > bv[c]) { bv[c] = x; bi4[c] = base + 5; }
            x = a1.z + tr[base + 6]; if (x > bv[c]) { bv[c] = x; bi4[c] = base + 6; }
            x = a1.w + tr[base + 7]; if (x > bv[c]) { bv[c] = x; bi4[c] = base + 7; }
        }
        float best = bv[0]; int bp = bi4[0];
#pragma unroll
        for (int c = 1; c < 4; ++c) { if (bv[c] > best) { best = bv[c]; bp = bi4[c]; } }
        bp += q * 32;                      // absolute prev index

        // DPP quad combine (value + index). Tie-break identical to proven version:
        // even q: strict > keeps own (lower prev range); odd q: >= takes lower partner.
        float v1 = dpp_xor1_f(best); int b1 = dpp_xor1_i(bp);
        bool  t1 = (q & 1) ? (v1 >= best) : (v1 > best);
        float m1 = t1 ? v1 : best;   int p1 = t1 ? b1 : bp;
        float v2 = dpp_xor2_f(m1);   int b2 = dpp_xor2_i(p1);
        bool  t2 = (q & 2) ? (v2 >= m1) : (v2 > m1);
        Mo  = t2 ? v2 : m1;          BPo = t2 ? b2 : p1;
    };

    // prologue (helpers): rows 0..15 -> buf0; rows 16..31 -> R0/R1
    float4 R0, R1;
    if (!comp) {
        R0 = pb4[hw2 * 32 + l32];
        R1 = pb4[(8 + hw2) * 32 + l32];
        normrow(R0, &prob[0][hw2][0]);
        normrow(R1, &prob[0][hw2 + 8][0]);
        R0 = pb4[(16 + hw2) * 32 + l32];
        R1 = pb4[(24 + hw2) * 32 + l32];
    }
    __syncthreads();

    const int nG = (len + 15) >> 4;
    for (int g = 0; g < nG; ++g) {
        const int tb = g << 4;
        if (!comp) {
            // normalize rows of group g+1 (loaded last group) -> buf[(g+1)&1]
            normrow(R0, &prob[(g + 1) & 1][hw2][0]);
            normrow(R1, &prob[(g + 1) & 1][hw2 + 8][0]);
            // issue raw loads for group g+2 (stay in flight across step barriers)
            int r0 = tb + 32 + hw2;     if (r0 > TT - 1) r0 = TT - 1;
            int r1 = tb + 32 + 8 + hw2; if (r1 > TT - 1) r1 = TT - 1;
            R0 = pb4[r0 * 32 + l32];
            R1 = pb4[r1 * 32 + l32];
        }
#pragma unroll 4
        for (int k = 0; k < 16; ++k) {
            const int t = tb + k;
            if (t < len) {                         // uniform per block
                if (comp) {
                    // Pv for the cur this lane will write (q0->cp, q1->cp+64)
                    const float Pv = prob[g & 1][k][(q & 1) ? cp + 64 : cp];
                    const float* ra = alpha[t & 1];
                    float*       wa = alpha[(t & 1) ^ 1];
                    const float4* a4 = (const float4*)(ra + q * 36);  // banks 0/4/8/12 per quarter
                    float4 av[8];
#pragma unroll
                    for (int i = 0; i < 8; ++i) av[i] = a4[i];   // quarter read ONCE

                    float Ma, Mb; int BPa, BPb;
                    curchain(av, trA, Ma, BPa);    // cur = cp
                    curchain(av, trB, Mb, BPb);    // cur = cp + 64

                    // all 4 quad lanes hold (Ma,BPa,Mb,BPb): spread the writes
                    const bool isB = q & 1;
                    const int  curw = isB ? cp + 64 : cp;
                    if (q < 2) {
                        wa[ASLOT(curw)] = (isB ? Mb : Ma) + Pv;
                    } else if (t >= 1) {
                        const int BPw = isB ? BPb : BPa;
                        if (t < TSPLIT) bps[(t - 1) * NN + curw] = (unsigned char)BPw;
                        else if (USE_WS) spb[(t - TSPLIT) * NN + curw] = (unsigned char)BPw;
                        else             spb[(size_t)t * 512 + curw] = (unsigned char)BPw;
                    }
                }
                STEP_BARRIER();    // lgkmcnt(0) only — global prefetch stays in flight
            }
        }
    }

    __threadfence();   // spilled bp global writes visible to this block's readers

    // terminal: argmax(alpha + trans0[EOS][:]), first-max tie-break
    if (tid < NN) {
        float v = alpha[len & 1][ASLOT(tid)] + trans[EOS_IDX * NN + tid];
        int idx = tid;
#pragma unroll
        for (int off = 32; off; off >>= 1) {
            float ov = __shfl_xor(v, off, 64);
            int   oi = __shfl_xor(idx, off, 64);
            if (ov > v || (ov == v && oi < idx)) { v = ov; idx = oi; }
        }
        if (lane == 0) { fin_v[wv] = v; fin_i[wv] = idx; }
    }
    __syncthreads();   // fin ready; full drain (incl. vmcnt) of forward traffic

    const int lenU = __builtin_amdgcn_readfirstlane(len);

    for (int t = lenU + tid; t < TT; t += 512) out[(size_t)b * TT + t] = 0.0f;

    // stage spilled bp steps [TSPLIT, TSPLIT+128) into the (now free) prob LDS.
    {
        unsigned int* cache = (unsigned int*)&prob[0][0][0];          // 16384 B, exact fit
        const volatile unsigned int* src = (const volatile unsigned int*)spb;
        for (int i = tid; i < 128 * 32; i += 512) {
            if (USE_WS) cache[i] = src[(size_t)(i >> 5) * 32 + (i & 31)];
            else        cache[i] = src[(size_t)(TSPLIT + (i >> 5)) * 128 + (i & 31)];
        }
    }
    __syncthreads();

    // terminal winner (uniform across threads)
    float sc; int T0;
    {
        float v0 = fin_v[0], v1 = fin_v[1];
        int   i0 = fin_i[0], i1 = fin_i[1];
        if (v1 > v0) { sc = v1; T0 = i1; }
        else         { sc = v0; T0 = i0; }
    }
    if (tid == 0) {
        out[(size_t)BB * TT + b] = sc;
        out[(size_t)b * TT + (lenU - 1)] = (float)T0;
    }

    // ---------- parallel hypothesis backtrace ----------
    // 8 segments of 64 links; wave s chases segment s for all 128 entry tags
    // (2 hypotheses/lane), replaying the exact same byte loads as a serial chase.
    const unsigned char* cacheb = (const unsigned char*)&prob[0][0][0];
    unsigned char* lt   = (unsigned char*)&alpha[0][0];   // last_tag[8][128] overlay (alpha dead)
    unsigned char* Harr = lt + 1024;                      // H[8] overlay

    const int s  = wv;                     // segment id 0..7
    const int A  = lenU - 1 - 64 * s;      // anchor time of this segment
    const int h0 = lane;                   // hypothesis tags
    const int h1 = 64 + lane;
    const int Jmax = (A < 64) ? A : 64;    // links to follow (A<1 -> none)

    unsigned int rec0[16], rec1[16];
#pragma unroll
    for (int i = 0; i < 16; ++i) { rec0[i] = 0u; rec1[i] = 0u; }

    int c0 = h0, c1 = h1;
#pragma unroll
    for (int j = 1; j <= 64; ++j) {
        if (j <= Jmax) {                   // wave-uniform
            const int x = A - j + 1;       // step whose bp we read -> tag at time A-j
            int n0, n1;
            if (x < TSPLIT) {
                n0 = bps[(x - 1) * NN + c0];
                n1 = bps[(x - 1) * NN + c1];
            } else if (x < TSPLIT + 128) {
                n0 = cacheb[(x - TSPLIT) * NN + c0];
                n1 = cacheb[(x - TSPLIT) * NN + c1];
            } else {
                if (USE_WS) {
                    n0 = ((const volatile unsigned char*)spb)[(size_t)(x - TSPLIT) * NN + c0];
                    n1 = ((const volatile unsigned char*)spb)[(size_t)(x - TSPLIT) * NN + c1];
                } else {
                    n0 = ((const volatile unsigned char*)spb)[(size_t)x * 512 + c0];
                    n1 = ((const volatile unsigned char*)spb)[(size_t)x * 512 + c1];
                }
            }
            c0 = n0; c1 = n1;
            rec0[(j - 1) >> 2] |= (unsigned int)c0 << (((j - 1) & 3) * 8);
            rec1[(j - 1) >> 2] |= (unsigned int)c1 << (((j - 1) & 3) * 8);
        }
    }
    if (A >= 65) {                         // tag at A-64 feeds segment s+1's stitch
        lt[s * NN + h0] = (unsigned char)c0;
        lt[s * NN + h1] = (unsigned char)c1;
    }
    __syncthreads();

    if (tid == 0) {
        int H = T0;
        Harr[0] = (unsigned char)H;
#pragma unroll
        for (int ss = 1; ss < 8; ++ss) {
            if (lenU - 1 - 64 * ss >= 1) {
                H = lt[(ss - 1) * NN + H];
                Harr[ss] = (unsigned char)H;
            }
        }
    }
    __syncthreads();

    if (A >= 1) {
        const int Hs = Harr[s];
        if (h0 == Hs) {
#pragma unroll
            for (int j = 1; j <= 64; ++j)
                if (j <= Jmax)
                    out[(size_t)b * TT + (A - j)] =
                        (float)((rec0[(j - 1) >> 2] >> (((j - 1) & 3) * 8)) & 255u);
        }
        if (h1 == Hs) {
#pragma unroll
            for (int j = 1; j <= 64; ++j)
                if (j <= Jmax)
                    out[(size_t)b * TT + (A - j)] =
                        (float)((rec1[(j - 1) >> 2] >> (((j - 1) & 3) * 8)) & 255u);
        }
    }
}

extern "C" void kernel_launch(void* const* d_in, const int* in_sizes, int n_in,
                              void* d_out, int out_size, void* d_ws, size_t ws_size,
                              hipStream_t stream) {
    float*       unaries = (float*)d_in[0];
    const float* trans   = (const float*)d_in[1];
    const int*   lengths = (const int*)d_in[2];
    float* out = (float*)d_out;
    unsigned char* ws = (unsigned char*)d_ws;

    const size_t need = (size_t)BB * (TT - TSPLIT) * NN;   // 4,718,592 B
    if (ws != nullptr && ws_size >= need) {
        hipLaunchKernelGGL(HIP_KERNEL_NAME(viterbi_kernel<1>), dim3(BB), dim3(512), 0, stream,
                           unaries, trans, lengths, out, ws);
    } else {
        hipLaunchKernelGGL(HIP_KERNEL_NAME(viterbi_kernel<0>), dim3(BB), dim3(512), 0, stream,
                           unaries, trans, lengths, out, ws);
    }
}

// Round 9
// 462.081 us; speedup vs baseline: 1.2456x; 1.2434x over previous
//
#include <hip/hip_runtime.h>

#define BB 256
#define TT 512
#define NN 128
#define GO_IDX 1
#define EOS_IDX 2
#define TSPLIT 368            // bp steps t in [1,TSPLIT) in LDS; [TSPLIT,512) spilled (ws or consumed unary rows)
#define NEGV (-10000.0f)
// padded alpha slot: x + (x>>5)*4  -> quarter bases at 0,36,72,108 (banks 0,4,8,12; 16B aligned)
#define ASLOT(x) ((x) + (((x) >> 5) << 2))

// step barrier: drain LDS only (alpha/bps/prob), leave global prefetch loads in flight.
#define STEP_BARRIER() asm volatile("s_waitcnt lgkmcnt(0)\n\ts_barrier" ::: "memory")

// ---------- DPP quad_perm helpers ----------
__device__ __forceinline__ float dpp_xor1_f(float x) {      // quad_perm [1,0,3,2]
    return __int_as_float(__builtin_amdgcn_update_dpp(0, __float_as_int(x), 0xB1, 0xF, 0xF, true));
}
__device__ __forceinline__ float dpp_xor2_f(float x) {      // quad_perm [2,3,0,1]
    return __int_as_float(__builtin_amdgcn_update_dpp(0, __float_as_int(x), 0x4E, 0xF, 0xF, true));
}
__device__ __forceinline__ int dpp_xor1_i(int x) {
    return __builtin_amdgcn_update_dpp(0, x, 0xB1, 0xF, 0xF, true);
}
__device__ __forceinline__ int dpp_xor2_i(int x) {
    return __builtin_amdgcn_update_dpp(0, x, 0x4E, 0xF, 0xF, true);
}

// ---------- fused kernel: in-flight log_softmax + serial Viterbi ----------
// Round-2 proven structure. Round-8 changes (both bit-exact):
//  (a) (val,idx) TREE reduction replaces the 8-deep serial compare chains.
//      Tie-break proof: serial first-max == lowest-index-among-maxima; tree
//      nodes take the right operand only on strict > (left = lower indices),
//      and that operator is associative -> identical value AND index.
//  (b) the 16 Pv values of a group are prefetched into registers at group
//      top, removing the per-step prob read from the critical path.
// USE_WS=1: bp spill to d_ws; USE_WS=0: spill into consumed unary rows.
template <int USE_WS>
__global__ __launch_bounds__(512) void viterbi_kernel(
    float* __restrict__ u,               // [B,T,N] RAW unaries
    const float* __restrict__ trans,     // [1,N,N] trans0[cur][prev]
    const int*   __restrict__ lengths_raw,
    float* __restrict__ out,             // [B*T] preds then [B] scores
    unsigned char* __restrict__ ws)      // spill: [B][144][128] bytes when USE_WS
{
    __shared__ unsigned char bps[(TSPLIT - 1) * NN];   // 46976 B (steps 1..367 at row t-1)
    __shared__ __align__(16) float prob[2][16][NN];    // 16384 B, normalized rows (dbuf); reused as bp cache
    __shared__ __align__(16) float alpha[2][144];      // 1152 B; reused as last_tag/H tables in epilogue
    __shared__ float fin_v[2];
    __shared__ int   fin_i[2];

    const int tid  = threadIdx.x;
    const int b    = blockIdx.x;
    const int wave = tid >> 6;
    const int lane = tid & 63;
    const int q    = tid & 3;              // prev-quarter owned by this lane
    const int cur  = tid >> 2;             // tag owned by this quad (0..127)
    const int hw   = tid >> 5;             // half-wave id 0..15 (lsm row owner)
    const int l32  = tid & 31;

    int len;
    {
        int probe = lengths_raw[1];        // ==0 iff int64 (lengths >= 256 > 0)
        len = (probe == 0) ? lengths_raw[2 * b] : lengths_raw[b];
    }

    float* pb = u + (size_t)b * TT * NN;
    const float4* pb4 = (const float4*)pb;
    unsigned char* spb = USE_WS ? (ws + (size_t)b * ((TT - TSPLIT) * NN)) : (unsigned char*)pb;

    // trans chunk in registers: trans0[cur][q*32 + j], j in [0,32)
    float tr[32];
    {
        const float4* t4 = (const float4*)(trans + cur * NN + q * 32);
#pragma unroll
        for (int i = 0; i < 8; ++i) {
            float4 v = t4[i];
            tr[4*i+0] = v.x; tr[4*i+1] = v.y; tr[4*i+2] = v.z; tr[4*i+3] = v.w;
        }
    }

    if (tid < NN) alpha[0][ASLOT(tid)] = (tid == GO_IDX) ? 0.0f : NEGV;

    // per-row log_softmax, bitwise-identical to the proven math
    auto normrow = [&](float4 v, float* dstrow) {
        float m = fmaxf(fmaxf(v.x, v.y), fmaxf(v.z, v.w));
#pragma unroll
        for (int off = 16; off; off >>= 1) m = fmaxf(m, __shfl_xor(m, off, 64));
        float s = expf(v.x - m) + expf(v.y - m) + expf(v.z - m) + expf(v.w - m);
#pragma unroll
        for (int off = 16; off; off >>= 1) s += __shfl_xor(s, off, 64);
        float ls = logf(s);
        ((float4*)dstrow)[l32] =
            make_float4((v.x - m) - ls, (v.y - m) - ls, (v.z - m) - ls, (v.w - m) - ls);
    };

    // prologue: rows 0..15 -> buf0; rows 16..31 -> R (normalized at top of g=0)
    float4 R = pb4[hw * 32 + l32];
    normrow(R, &prob[0][hw][0]);
    R = pb4[(16 + hw) * 32 + l32];
    __syncthreads();

    const int nG = (len + 15) >> 4;
    for (int g = 0; g < nG; ++g) {
        const int tb = g << 4;
        // Pv register prefetch for the whole group (written during g-1, synced)
        float Pg[16];
#pragma unroll
        for (int k2 = 0; k2 < 16; ++k2) Pg[k2] = prob[g & 1][k2][cur];
        // normalize rows of group g+1 (loaded last group) -> buf[(g+1)&1].
        normrow(R, &prob[(g + 1) & 1][hw][0]);
        // issue raw loads for group g+2 (stay in flight across step barriers)
        {
            int rr = tb + 32 + hw;
            if (rr > TT - 1) rr = TT - 1;   // clamped row never normalized/used
            R = pb4[rr * 32 + l32];
        }
#pragma unroll 4
        for (int k = 0; k < 16; ++k) {
            const int t = tb + k;
            if (t < len) {                         // uniform per block
                const float* ra = alpha[t & 1];
                float*       wa = alpha[(t & 1) ^ 1];
                const float4* a4 = (const float4*)(ra + q * 36);  // banks 0/4/8/12 per quarter
                // 32 adds (same values as proven serial version)
                float v[32];
#pragma unroll
                for (int i = 0; i < 8; ++i) {
                    float4 a = a4[i];
                    v[4*i+0] = a.x + tr[4*i+0];
                    v[4*i+1] = a.y + tr[4*i+1];
                    v[4*i+2] = a.z + tr[4*i+2];
                    v[4*i+3] = a.w + tr[4*i+3];
                }
                // (val,idx) tree, strict > toward the right (higher-index) arm:
                // == lowest-index-among-maxima == proven serial first-max.
                float m1[16]; int i1[16];
#pragma unroll
                for (int j = 0; j < 16; ++j) {
                    bool tk = v[2*j+1] > v[2*j];
                    m1[j] = tk ? v[2*j+1] : v[2*j];
                    i1[j] = tk ? 2*j+1 : 2*j;
                }
                float m2[8]; int i2[8];
#pragma unroll
                for (int j = 0; j < 8; ++j) {
                    bool tk = m1[2*j+1] > m1[2*j];
                    m2[j] = tk ? m1[2*j+1] : m1[2*j];
                    i2[j] = tk ? i1[2*j+1] : i1[2*j];
                }
                float m3[4]; int i3[4];
#pragma unroll
                for (int j = 0; j < 4; ++j) {
                    bool tk = m2[2*j+1] > m2[2*j];
                    m3[j] = tk ? m2[2*j+1] : m2[2*j];
                    i3[j] = tk ? i2[2*j+1] : i2[2*j];
                }
                float m4[2]; int i4[2];
#pragma unroll
                for (int j = 0; j < 2; ++j) {
                    bool tk = m3[2*j+1] > m3[2*j];
                    m4[j] = tk ? m3[2*j+1] : m3[2*j];
                    i4[j] = tk ? i3[2*j+1] : i3[2*j];
                }
                bool tk5 = m4[1] > m4[0];
                float best = tk5 ? m4[1] : m4[0];
                int   bp   = (tk5 ? i4[1] : i4[0]) + q * 32;   // absolute prev index

                // DPP quad combine (value + index). Tie-break identical to proven:
                // even q: strict > keeps own (lower prev range); odd q: >= takes lower partner.
                float v1 = dpp_xor1_f(best); int b1 = dpp_xor1_i(bp);
                bool  t1 = (q & 1) ? (v1 >= best) : (v1 > best);
                float mm1 = t1 ? v1 : best;  int p1 = t1 ? b1 : bp;
                float v2 = dpp_xor2_f(mm1);  int b2 = dpp_xor2_i(p1);
                bool  t2 = (q & 2) ? (v2 >= mm1) : (v2 > mm1);
                float M  = t2 ? v2 : mm1;    int BP = t2 ? b2 : p1;

                if (q == 0) {
                    wa[ASLOT(cur)] = M + Pg[k];
                    if (t >= 1) {
                        if (t < TSPLIT) bps[(t - 1) * NN + cur] = (unsigned char)BP;
                        else if (USE_WS) spb[(t - TSPLIT) * NN + cur] = (unsigned char)BP;
                        else             spb[(size_t)t * 512 + cur] = (unsigned char)BP;
                    }
                }
                STEP_BARRIER();    // lgkmcnt(0) only — global prefetch stays in flight
            }
        }
    }

    __threadfence();   // spilled bp global writes visible to this block's readers

    // terminal: argmax(alpha + trans0[EOS][:]), first-max tie-break
    if (tid < NN) {
        float v = alpha[len & 1][ASLOT(tid)] + trans[EOS_IDX * NN + tid];
        int idx = tid;
#pragma unroll
        for (int off = 32; off; off >>= 1) {
            float ov = __shfl_xor(v, off, 64);
            int   oi = __shfl_xor(idx, off, 64);
            if (ov > v || (ov == v && oi < idx)) { v = ov; idx = oi; }
        }
        if (lane == 0) { fin_v[wave] = v; fin_i[wave] = idx; }
    }
    __syncthreads();   // fin ready; full drain (incl. vmcnt) of forward traffic

    const int lenU = __builtin_amdgcn_readfirstlane(len);

    for (int t = lenU + tid; t < TT; t += 512) out[(size_t)b * TT + t] = 0.0f;

    // stage spilled bp steps [TSPLIT, TSPLIT+128) into the (now free) prob LDS.
    {
        unsigned int* cache = (unsigned int*)&prob[0][0][0];          // 16384 B, exact fit
        const volatile unsigned int* src = (const volatile unsigned int*)spb;
        for (int i = tid; i < 128 * 32; i += 512) {
            if (USE_WS) cache[i] = src[(size_t)(i >> 5) * 32 + (i & 31)];
            else        cache[i] = src[(size_t)(TSPLIT + (i >> 5)) * 128 + (i & 31)];
        }
    }
    __syncthreads();

    // terminal winner (uniform across threads)
    float sc; int T0;
    {
        float v0 = fin_v[0], v1 = fin_v[1];
        int   i0 = fin_i[0], i1 = fin_i[1];
        if (v1 > v0) { sc = v1; T0 = i1; }
        else         { sc = v0; T0 = i0; }
    }
    if (tid == 0) {
        out[(size_t)BB * TT + b] = sc;
        out[(size_t)b * TT + (lenU - 1)] = (float)T0;
    }

    // ---------- parallel hypothesis backtrace ----------
    // 8 segments of 64 links; wave s chases segment s for all 128 entry tags
    // (2 hypotheses/lane), replaying the exact same byte loads as a serial chase.
    const unsigned char* cacheb = (const unsigned char*)&prob[0][0][0];
    unsigned char* lt   = (unsigned char*)&alpha[0][0];   // last_tag[8][128] overlay (alpha dead)
    unsigned char* Harr = lt + 1024;                      // H[8] overlay

    const int s  = wave;                   // segment id 0..7
    const int A  = lenU - 1 - 64 * s;      // anchor time of this segment
    const int h0 = lane;                   // hypothesis tags
    const int h1 = 64 + lane;
    const int Jmax = (A < 64) ? A : 64;    // links to follow (A<1 -> none)

    unsigned int rec0[16], rec1[16];
#pragma unroll
    for (int i = 0; i < 16; ++i) { rec0[i] = 0u; rec1[i] = 0u; }

    int c0 = h0, c1 = h1;
#pragma unroll
    for (int j = 1; j <= 64; ++j) {
        if (j <= Jmax) {                   // wave-uniform
            const int x = A - j + 1;       // step whose bp we read -> tag at time A-j
            int n0, n1;
            if (x < TSPLIT) {
                n0 = bps[(x - 1) * NN + c0];
                n1 = bps[(x - 1) * NN + c1];
            } else if (x < TSPLIT + 128) {
                n0 = cacheb[(x - TSPLIT) * NN + c0];
                n1 = cacheb[(x - TSPLIT) * NN + c1];
            } else {
                if (USE_WS) {
                    n0 = ((const volatile unsigned char*)spb)[(size_t)(x - TSPLIT) * NN + c0];
                    n1 = ((const volatile unsigned char*)spb)[(size_t)(x - TSPLIT) * NN + c1];
                } else {
                    n0 = ((const volatile unsigned char*)spb)[(size_t)x * 512 + c0];
                    n1 = ((const volatile unsigned char*)spb)[(size_t)x * 512 + c1];
                }
            }
            c0 = n0; c1 = n1;
            rec0[(j - 1) >> 2] |= (unsigned int)c0 << (((j - 1) & 3) * 8);
            rec1[(j - 1) >> 2] |= (unsigned int)c1 << (((j - 1) & 3) * 8);
        }
    }
    if (A >= 65) {                         // tag at A-64 feeds segment s+1's stitch
        lt[s * NN + h0] = (unsigned char)c0;
        lt[s * NN + h1] = (unsigned char)c1;
    }
    __syncthreads();

    if (tid == 0) {
        int H = T0;
        Harr[0] = (unsigned char)H;
#pragma unroll
        for (int ss = 1; ss < 8; ++ss) {
            if (lenU - 1 - 64 * ss >= 1) {
                H = lt[(ss - 1) * NN + H];
                Harr[ss] = (unsigned char)H;
            }
        }
    }
    __syncthreads();

    if (A >= 1) {
        const int Hs = Harr[s];
        if (h0 == Hs) {
#pragma unroll
            for (int j = 1; j <= 64; ++j)
                if (j <= Jmax)
                    out[(size_t)b * TT + (A - j)] =
                        (float)((rec0[(j - 1) >> 2] >> (((j - 1) & 3) * 8)) & 255u);
        }
        if (h1 == Hs) {
#pragma unroll
            for (int j = 1; j <= 64; ++j)
                if (j <= Jmax)
                    out[(size_t)b * TT + (A - j)] =
                        (float)((rec1[(j - 1) >> 2] >> (((j - 1) & 3) * 8)) & 255u);
        }
    }
}

extern "C" void kernel_launch(void* const* d_in, const int* in_sizes, int n_in,
                              void* d_out, int out_size, void* d_ws, size_t ws_size,
                              hipStream_t stream) {
    float*       unaries = (float*)d_in[0];
    const float* trans   = (const float*)d_in[1];
    const int*   lengths = (const int*)d_in[2];
    float* out = (float*)d_out;
    unsigned char* ws = (unsigned char*)d_ws;

    const size_t need = (size_t)BB * (TT - TSPLIT) * NN;   // 4,718,592 B
    if (ws != nullptr && ws_size >= need) {
        hipLaunchKernelGGL(HIP_KERNEL_NAME(viterbi_kernel<1>), dim3(BB), dim3(512), 0, stream,
                           unaries, trans, lengths, out, ws);
    } else {
        hipLaunchKernelGGL(HIP_KERNEL_NAME(viterbi_kernel<0>), dim3(BB), dim3(512), 0, stream,
                           unaries, trans, lengths, out, ws);
    }
}